// Round 4
// baseline (928.203 us; speedup 1.0000x reference)
//
#include <hip/hip_runtime.h>
#include <cstdint>
#include <cstddef>

#define D_MODEL 2048
#define D_FFN   8192
#define RANK    16
#define EPS     1e-6f
#define MOD_SCALE 0.1f

typedef float    f32x4 __attribute__((ext_vector_type(4)));
typedef _Float16 half8 __attribute__((ext_vector_type(8)));

// Async global->LDS, 16B per lane. LDS dest is wave-uniform base + lane*16;
// the GLOBAL address is per-lane, so we XOR-swizzle the source 16B chunk
// (c ^ (row&7)) for bank-conflict-free ds_read_b128 later, at zero cost.
// Proven conflict-free ONLY with the 16x16 quad-based fragment addressing
// (frag64 below). Geometry everywhere: 64-half (128 B) row stride.
__device__ __forceinline__ void async_load16(const void* g, void* l) {
  __builtin_amdgcn_global_load_lds(
      (const __attribute__((address_space(1))) uint32_t*)g,
      (__attribute__((address_space(3))) uint32_t*)l,
      16, 0, 0);
}

// Stage one 64-row x 64-half (8 KB) round; 512 threads x 16 B.
__device__ __forceinline__ void stage_round(const _Float16* __restrict__ g,
                                            size_t stride, _Float16* l, int tid) {
  const int row = tid >> 3;
  const int cs  = (tid & 7) ^ (row & 7);
  async_load16(g + (size_t)row * stride + (size_t)cs * 8, l + tid * 8);
}

// Read 8-half fragment at (row, 8-half chunk ck) from a swizzled 64-wide tile.
__device__ __forceinline__ half8 frag64(const _Float16* base, int row, int ck) {
  return *(const half8*)&base[row * 64 + ((ck ^ (row & 7)) * 8)];
}

#define PRIO1() __builtin_amdgcn_s_setprio(1)
#define PRIO0() __builtin_amdgcn_s_setprio(0)
#define VMW(n)  asm volatile("s_waitcnt vmcnt(" #n ")" ::: "memory")
// Raw barrier WITH compiler memory fence (no waitcnt drain emitted, unlike
// __syncthreads): no LDS/global op may be moved across it by the scheduler.
#define BARM()  asm volatile("s_barrier" ::: "memory")

// ---------------------------------------------------------------------------
// Fused fp32 -> f16 convert for all three big weights (one launch).
// ---------------------------------------------------------------------------
__global__ __launch_bounds__(256) void convert3_f32_f16(
    const float* __restrict__ s0, const float* __restrict__ s1,
    const float* __restrict__ s2,
    _Float16* __restrict__ d0, _Float16* __restrict__ d1,
    _Float16* __restrict__ d2)
{
  const int w = blockIdx.x >> 13;
  const float*   s = (w == 0) ? s0 : (w == 1) ? s1 : s2;
  _Float16*      d = (w == 0) ? d0 : (w == 1) ? d1 : d2;
  size_t i = ((size_t)(blockIdx.x & 8191) * 256 + threadIdx.x) * 8;
  f32x4 a = *(const f32x4*)(s + i);
  f32x4 b = *(const f32x4*)(s + i + 4);
  half8 h;
  #pragma unroll
  for (int j = 0; j < 4; ++j) { h[j] = (_Float16)a[j]; h[4+j] = (_Float16)b[j]; }
  *(half8*)(d + i) = h;
}

__global__ __launch_bounds__(256) void convert_f32_f16(
    const float* __restrict__ s, _Float16* __restrict__ d)
{
  size_t i = ((size_t)blockIdx.x * 256 + threadIdx.x) * 8;
  f32x4 a = *(const f32x4*)(s + i);
  f32x4 b = *(const f32x4*)(s + i + 4);
  half8 h;
  #pragma unroll
  for (int j = 0; j < 4; ++j) { h[j] = (_Float16)a[j]; h[4+j] = (_Float16)b[j]; }
  *(half8*)(d + i) = h;
}

// ---------------------------------------------------------------------------
// Kernel 1: per-token RMSNorm -> h (f16), c[m,r] = (h.A)[r] * 0.1*tanh((attn.A)[r])
// ---------------------------------------------------------------------------
__global__ __launch_bounds__(256) void prep_kernel(
    const float* __restrict__ hs, const float* __restrict__ attn,
    const float* __restrict__ Amat, const float* __restrict__ gamma,
    _Float16* __restrict__ h16, float* __restrict__ cmat)
{
  const int token = blockIdx.x;
  const int tid   = threadIdx.x;
  const int lane  = tid & 63;
  const int wv    = tid >> 6;
  const size_t tb = (size_t)token * D_MODEL;
  const int base  = tid * 8;

  f32x4 x0 = *(const f32x4*)(hs + tb + base);
  f32x4 x1 = *(const f32x4*)(hs + tb + base + 4);
  f32x4 a0 = *(const f32x4*)(attn + tb + base);
  f32x4 a1 = *(const f32x4*)(attn + tb + base + 4);

  float ss = 0.f;
  #pragma unroll
  for (int j = 0; j < 4; ++j) ss += x0[j]*x0[j] + x1[j]*x1[j];
  #pragma unroll
  for (int off = 32; off > 0; off >>= 1) ss += __shfl_xor(ss, off, 64);

  __shared__ float red[4];
  __shared__ float redp[4][RANK];
  __shared__ float redh[4][RANK];
  if (lane == 0) red[wv] = ss;
  __syncthreads();
  const float tot = red[0] + red[1] + red[2] + red[3];
  const float rms = rsqrtf(tot * (1.0f / D_MODEL) + EPS);

  f32x4 g0 = *(const f32x4*)(gamma + base);
  f32x4 g1 = *(const f32x4*)(gamma + base + 4);
  float hv[8], av[8];
  #pragma unroll
  for (int j = 0; j < 4; ++j) {
    hv[j]   = x0[j] * rms * g0[j];
    hv[4+j] = x1[j] * rms * g1[j];
    av[j]   = a0[j];
    av[4+j] = a1[j];
  }
  half8 hh;
  #pragma unroll
  for (int j = 0; j < 8; ++j) hh[j] = (_Float16)hv[j];
  *(half8*)(h16 + tb + base) = hh;

  float pa[RANK], ph[RANK];
  #pragma unroll
  for (int r = 0; r < RANK; ++r) { pa[r] = 0.f; ph[r] = 0.f; }
  #pragma unroll
  for (int e = 0; e < 8; ++e) {
    const f32x4* Ar = (const f32x4*)(Amat + (size_t)(base + e) * RANK);
    #pragma unroll
    for (int q = 0; q < 4; ++q) {
      f32x4 ar = Ar[q];
      #pragma unroll
      for (int j = 0; j < 4; ++j) {
        pa[q*4+j] += av[e] * ar[j];
        ph[q*4+j] += hv[e] * ar[j];
      }
    }
  }
  #pragma unroll
  for (int r = 0; r < RANK; ++r) {
    #pragma unroll
    for (int off = 32; off > 0; off >>= 1) {
      pa[r] += __shfl_xor(pa[r], off, 64);
      ph[r] += __shfl_xor(ph[r], off, 64);
    }
  }
  if (lane == 0) {
    #pragma unroll
    for (int r = 0; r < RANK; ++r) { redp[wv][r] = pa[r]; redh[wv][r] = ph[r]; }
  }
  __syncthreads();
  if (tid < RANK) {
    float sp = redp[0][tid] + redp[1][tid] + redp[2][tid] + redp[3][tid];
    float sh = redh[0][tid] + redh[1][tid] + redh[2][tid] + redh[3][tid];
    cmat[(size_t)token * RANK + tid] = sh * (MOD_SCALE * tanhf(sp));
  }
}

// ---------------------------------------------------------------------------
// Frag-read / MFMA helpers (all static indexing after inline).
// ---------------------------------------------------------------------------
__device__ __forceinline__ void rdA4(half8 (&d)[4], const _Float16* Ab,
                                     int lr, int ck) {
  #pragma unroll
  for (int im = 0; im < 4; ++im)
    d[im] = frag64(Ab, im*16 + lr, ck);
}
__device__ __forceinline__ void rdB2(half8 (&d)[2], const _Float16* Bb,
                                     int lr, int ck) {
  #pragma unroll
  for (int inn = 0; inn < 2; ++inn)
    d[inn] = frag64(Bb, inn*16 + lr, ck);
}
// 8 MFMA: 4 m-frags x 2 n-frags, single k-chunk.
__device__ __forceinline__ void mm8(f32x4 (&acc)[8][2], int mb,
                                    const half8 (&a)[4], const half8 (&b)[2]) {
  #pragma unroll
  for (int im = 0; im < 4; ++im)
    #pragma unroll
    for (int inn = 0; inn < 2; ++inn)
      acc[mb+im][inn] = __builtin_amdgcn_mfma_f32_16x16x32_f16(
          a[im], b[inn], acc[mb+im][inn], 0, 0, 0);
}
// 16 MFMA: 4 m-frags x 4 n-frags, single k-chunk.
__device__ __forceinline__ void mm16(f32x4 (&acc)[4][4],
                                     const half8 (&a)[4], const half8 (&b)[4]) {
  #pragma unroll
  for (int im = 0; im < 4; ++im)
    #pragma unroll
    for (int inn = 0; inn < 4; ++inn)
      acc[im][inn] = __builtin_amdgcn_mfma_f32_16x16x32_f16(
          a[im], b[inn], acc[im][inn], 0, 0, 0);
}

// ---------------------------------------------------------------------------
// Kernel 2: dual GEMM, 256x128 tile, BK=64, 8 waves (2M x 4N).
// R4: REGISTER-PIPELINED sub-steps. Per K-tile, 4 sub-steps (m-half x k-chunk);
// sub-step s issues ds_reads for s+1 into fresh frags, then MFMAs s's frags.
// Compiler emits counted lgkmcnt(4/8) before each cluster (not 0): s+1's LDS
// service runs concurrently with s's MFMAs (separate pipes). This removes the
// read->use dependency that made R0-R3's phase schedules additive
// (LDS 2300cyc + MFMA 2483cyc per K-tile, measured 43% MfmaUtil).
// Cross-tile boundary: leading 12 reads after the barrier (preload across the
// barrier is illegal: waves read bytes staged by OTHER waves). Stage rounds
// for t+1 issued in sub-steps 0-1 so VMW(0) before the barrier is pre-landed.
// ---------------------------------------------------------------------------
#define BGOFF 16384
#define BUOFF 24576

__global__ __launch_bounds__(512, 2) void gemm_gateup(
    const _Float16* __restrict__ h16,
    const _Float16* __restrict__ Wg16, const _Float16* __restrict__ Wu16,
    const float* __restrict__ cmat, const float* __restrict__ Bmat,
    _Float16* __restrict__ tmat)
{
  __shared__ __align__(16) _Float16 lds[2][32768];   // 128 KB

  const int tid  = threadIdx.x;
  const int lane = tid & 63;
  const int wv   = tid >> 6;          // 0..7
  const int lr   = lane & 15;
  const int quad = lane >> 4;
  const int qb   = (wv >> 2) * 2;     // A quarter base: 0 or 2
  const int e    = wv & 3;            // B sub-tile (32 cols)
  const int wm   = (wv >> 2) * 128;   // wave row base in tile

  // XCD-partitioned mapping (native dispatch: lin%8 -> XCD):
  // xcd owns m-tiles {2*xcd, 2*xcd+1}; within-XCD order n-fast, m-pair inner.
  const int lin  = blockIdx.x;
  const int xcd  = lin & 7;
  const int r    = lin >> 3;                 // 0..127
  const int gm0  = (xcd * 2 + (r & 1)) * 256;
  const int gn0  = (r >> 1) * 128;

  f32x4 accG[8][2], accU[8][2];
  #pragma unroll
  for (int i = 0; i < 8; ++i)
    #pragma unroll
    for (int j = 0; j < 2; ++j) {
      f32x4 z = {0.f, 0.f, 0.f, 0.f};
      accG[i][j] = z; accU[i][j] = z;
    }

  // Half-tile stages (each = 2 stage_rounds = 2 vmcnt slots/thread).
#define STAE(b,t) do { \
    stage_round(h16 + (size_t)(gm0 +   0) * D_MODEL + (size_t)(t)*64, D_MODEL, &lds[b][0],     tid); \
    stage_round(h16 + (size_t)(gm0 + 128) * D_MODEL + (size_t)(t)*64, D_MODEL, &lds[b][8192],  tid); } while (0)
#define STAO(b,t) do { \
    stage_round(h16 + (size_t)(gm0 +  64) * D_MODEL + (size_t)(t)*64, D_MODEL, &lds[b][4096],  tid); \
    stage_round(h16 + (size_t)(gm0 + 192) * D_MODEL + (size_t)(t)*64, D_MODEL, &lds[b][12288], tid); } while (0)
#define STG(b,t) do { \
    stage_round(Wg16 + (size_t)(gn0 +  0) * D_MODEL + (size_t)(t)*64, D_MODEL, &lds[b][BGOFF],        tid); \
    stage_round(Wg16 + (size_t)(gn0 + 64) * D_MODEL + (size_t)(t)*64, D_MODEL, &lds[b][BGOFF + 4096], tid); } while (0)
#define STU(b,t) do { \
    stage_round(Wu16 + (size_t)(gn0 +  0) * D_MODEL + (size_t)(t)*64, D_MODEL, &lds[b][BUOFF],        tid); \
    stage_round(Wu16 + (size_t)(gn0 + 64) * D_MODEL + (size_t)(t)*64, D_MODEL, &lds[b][BUOFF + 4096], tid); } while (0)

  // One K-tile, register-pipelined. BUF compile-time; stages tile T1 -> SBUF.
  // Read schedule (k0 = chunk quad, k1 = chunk 4+quad):
  //   lead : a0(m0,k0), bg0, bu0      [12 reads]
  //   s0   : issue a1(m1,k0)          -> mm8 x2 on a0 (lgkmcnt(4))
  //   s1   : issue a2(m0,k1),bg1,bu1  -> mm8 x2 on a1 (lgkmcnt(8))
  //   s2   : issue a3(m1,k1)          -> mm8 x2 on a2 (lgkmcnt(4))
  //   s3   :                          -> mm8 x2 on a3 (lgkmcnt(0))
#define KTILE(BUF, SBUF, T1, DOSTG)                                        \
  {                                                                        \
    const _Float16* A_  = &lds[BUF][0];                                    \
    const _Float16* Bg_ = &lds[BUF][BGOFF + e * 2048];                     \
    const _Float16* Bu_ = &lds[BUF][BUOFF + e * 2048];                     \
    half8 a0[4], a1[4], a2[4], a3[4], bg0[2], bu0[2], bg1[2], bu1[2];      \
    rdA4(a0, A_ + qb * 4096, lr, quad);                                    \
    rdB2(bg0, Bg_, lr, quad);                                              \
    rdB2(bu0, Bu_, lr, quad);                                              \
    if (DOSTG) { STAE(SBUF, T1); STG(SBUF, T1); }                          \
    rdA4(a1, A_ + (qb + 1) * 4096, lr, quad);                              \
    PRIO1(); mm8(accG, 0, a0, bg0); mm8(accU, 0, a0, bu0); PRIO0();        \
    if (DOSTG) { STAO(SBUF, T1); STU(SBUF, T1); }                          \
    rdA4(a2, A_ + qb * 4096, lr, 4 + quad);                                \
    rdB2(bg1, Bg_, lr, 4 + quad);                                          \
    rdB2(bu1, Bu_, lr, 4 + quad);                                          \
    PRIO1(); mm8(accG, 4, a1, bg0); mm8(accU, 4, a1, bu0); PRIO0();        \
    rdA4(a3, A_ + (qb + 1) * 4096, lr, 4 + quad);                          \
    PRIO1(); mm8(accG, 0, a2, bg1); mm8(accU, 0, a2, bu1); PRIO0();        \
    PRIO1(); mm8(accG, 4, a3, bg1); mm8(accU, 4, a3, bu1); PRIO0();        \
    VMW(0); BARM();                                                        \
  }

  // Prologue: tile 0 staged and landed.
  STAE(0, 0); STAO(0, 0); STG(0, 0); STU(0, 0);
  VMW(0); BARM();

  #pragma unroll 1
  for (int i = 0; i < 16; ++i) {
    KTILE(0, 1, 2*i + 1, true);
    KTILE(1, 0, 2*i + 2, (i < 15));
  }

  // ---- rank-16 delta folded in as one zero-padded K=32 MFMA step into accG ----
  __syncthreads();   // full drain; loop is done
  _Float16* l0 = &lds[0][0];
  for (int i = tid; i < 8192; i += 512) {           // cbuf [256][32]
    int m = i >> 5, k = i & 31;
    l0[i] = (k < RANK) ? (_Float16)cmat[(size_t)(gm0 + m) * RANK + k] : (_Float16)0.f;
  }
  for (int i = tid; i < 4096; i += 512) {           // bbuf [128][32]
    int f = i >> 5, k = i & 31;
    l0[8192 + i] = (k < RANK) ? (_Float16)Bmat[(size_t)k * D_FFN + gn0 + f] : (_Float16)0.f;
  }
  __syncthreads();
  #pragma unroll
  for (int ai = 0; ai < 8; ++ai) {
    half8 cf = *(const half8*)&l0[(wm + ai*16 + lr) * 32 + quad * 8];
    #pragma unroll
    for (int inn = 0; inn < 2; ++inn) {
      half8 bd = *(const half8*)&l0[8192 + (e*32 + inn*16 + lr) * 32 + quad * 8];
      accG[ai][inn] = __builtin_amdgcn_mfma_f32_16x16x32_f16(cf, bd, accG[ai][inn], 0, 0, 0);
    }
  }

  // ---- Epilogue: t = silu(gate) * up ----
  #pragma unroll
  for (int ai = 0; ai < 8; ++ai)
    #pragma unroll
    for (int inn = 0; inn < 2; ++inn) {
      const int grow = gm0 + wm + ai*16 + quad*4;
      const int gcol = gn0 + e*32 + inn*16 + lr;
      #pragma unroll
      for (int rr = 0; rr < 4; ++rr) {
        float g = accG[ai][inn][rr];
        float u = accU[ai][inn][rr];
        float s = g / (1.0f + __expf(-g));
        tmat[(size_t)(grow + rr) * D_FFN + gcol] = (_Float16)(s * u);
      }
    }
#undef STAE
#undef STAO
#undef STG
#undef STU
#undef KTILE
}

// ---------------------------------------------------------------------------
// Kernel 3: out = hidden_states + t @ Wd16^T (K=8192). 256x128 tile, BK=64.
// R4: wave layout 4M x 2N (wave tile 64x64: LDS reads 128KB/K-tile vs 160KB
// at 2Mx4N, same MFMA count) + 2-sub-step register pipeline + 2-buffer LDS
// (96 KB). Grid = exactly 256 blocks (1/CU); XCD mapping keeps each XCD's
// 2 Wd n-panels (4MB) L2-resident.
// ---------------------------------------------------------------------------
__global__ __launch_bounds__(512, 2) void gemm_down(
    const _Float16* __restrict__ tmat, const _Float16* __restrict__ Wd16,
    const float* __restrict__ hs, float* __restrict__ out)
{
  __shared__ __align__(16) _Float16 lds[2][24576];   // 96 KB: A 16K halves | B 8K halves

  const int tid  = threadIdx.x;
  const int lane = tid & 63;
  const int wv   = tid >> 6;
  const int lr   = lane & 15;
  const int quad = lane >> 4;
  const int qa   = wv >> 1;           // A quarter (64 rows), 0..3
  const int e    = wv & 1;            // B half (64 cols), 0..1

  const int lin  = blockIdx.x;               // 256 blocks
  const int xcd  = lin & 7;
  const int r    = lin >> 3;                 // 0..31
  const int gn0  = (xcd * 2 + (r & 1)) * 128;
  const int gm0  = (r >> 1) * 256;

  f32x4 acc[4][4];
  #pragma unroll
  for (int i = 0; i < 4; ++i)
    #pragma unroll
    for (int j = 0; j < 4; ++j) {
      f32x4 z = {0.f, 0.f, 0.f, 0.f};
      acc[i][j] = z;
    }

#define DSTA(b,q,t) stage_round(tmat + (size_t)(gm0 + (q)*64) * D_FFN + (size_t)(t)*64, D_FFN, &lds[b][(q)*4096], tid)
#define DSTB(b,p,t) stage_round(Wd16 + (size_t)(gn0 + (p)*64) * D_FFN + (size_t)(t)*64, D_FFN, &lds[b][16384 + (p)*4096], tid)

  // One K-tile, register-pipelined (2 sub-steps of 16 MFMA each).
#define DKTILE(BUF, SBUF, T1, DOSTG)                                       \
  {                                                                        \
    const _Float16* A_ = &lds[BUF][qa * 4096];                             \
    const _Float16* B_ = &lds[BUF][16384 + e * 4096];                      \
    half8 a0[4], a1[4], b0[4], b1[4];                                      \
    rdA4(a0, A_, lr, quad);                                                \
    rdA4(b0, B_, lr, quad);                                                \
    if (DOSTG) { DSTA(SBUF, 0, T1); DSTA(SBUF, 1, T1); DSTA(SBUF, 2, T1); }\
    rdA4(a1, A_, lr, 4 + quad);                                            \
    rdA4(b1, B_, lr, 4 + quad);                                            \
    PRIO1(); mm16(acc, a0, b0); PRIO0();                                   \
    if (DOSTG) { DSTA(SBUF, 3, T1); DSTB(SBUF, 0, T1); DSTB(SBUF, 1, T1); }\
    PRIO1(); mm16(acc, a1, b1); PRIO0();                                   \
    VMW(0); BARM();                                                        \
  }

  // Prologue: tile 0 staged and landed.
  DSTA(0,0,0); DSTA(0,1,0); DSTA(0,2,0); DSTA(0,3,0); DSTB(0,0,0); DSTB(0,1,0);
  VMW(0); BARM();

  #pragma unroll 1
  for (int i = 0; i < 64; ++i) {
    DKTILE(0, 1, 2*i + 1, true);
    DKTILE(1, 0, 2*i + 2, (i < 63));
  }

  #pragma unroll
  for (int im = 0; im < 4; ++im)
    #pragma unroll
    for (int inn = 0; inn < 4; ++inn) {
      const int grow = gm0 + qa*64 + im*16 + quad*4;
      const int gcol = gn0 + e*64 + inn*16 + lr;
      #pragma unroll
      for (int rr = 0; rr < 4; ++rr) {
        size_t o = (size_t)(grow + rr) * D_MODEL + gcol;
        out[o] = hs[o] + acc[im][inn][rr];
      }
    }
#undef DSTA
#undef DSTB
#undef DKTILE
}

extern "C" void kernel_launch(void* const* d_in, const int* in_sizes, int n_in,
                              void* d_out, int out_size, void* d_ws, size_t ws_size,
                              hipStream_t stream) {
  const float* hs    = (const float*)d_in[0];
  const float* attn  = (const float*)d_in[1];
  const float* Amat  = (const float*)d_in[2];
  const float* Bmat  = (const float*)d_in[3];
  const float* Wg    = (const float*)d_in[4];
  const float* Wu    = (const float*)d_in[5];
  const float* Wd    = (const float*)d_in[6];
  const float* gamma = (const float*)d_in[7];
  float* out = (float*)d_out;

  const int M = in_sizes[0] / D_MODEL;        // 4096 tokens
  const size_t WD = (size_t)D_FFN * D_MODEL;  // elements per big weight

  char* ws = (char*)d_ws;
  _Float16* h16  = (_Float16*)ws;
  float*    cmat = (float*)(ws + (size_t)M * D_MODEL * 2);
  _Float16* tmat = (_Float16*)(ws + (size_t)M * D_MODEL * 2 + (size_t)M * RANK * 4);
  _Float16* wbuf = tmat + (size_t)M * D_FFN;
  _Float16* Wg16 = wbuf;
  _Float16* Wu16 = wbuf + WD;

  const size_t base_bytes = (size_t)M * D_MODEL * 2 + (size_t)M * RANK * 4
                          + (size_t)M * D_FFN * 2 + 2 * WD * 2;
  const bool sep_wd = (ws_size >= base_bytes + WD * 2);
  _Float16* Wd16 = sep_wd ? (wbuf + 2 * WD) : wbuf;   // else reuse Wg16 slot

  const int convBlocks = (int)(WD / (256 * 8));   // 8192 per weight

  prep_kernel<<<M, 256, 0, stream>>>(hs, attn, Amat, gamma, h16, cmat);
  if (sep_wd) {
    convert3_f32_f16<<<3 * convBlocks, 256, 0, stream>>>(Wg, Wu, Wd, Wg16, Wu16, Wd16);
    gemm_gateup<<<dim3((D_FFN / 128) * (M / 256)), 512, 0, stream>>>(h16, Wg16, Wu16, cmat, Bmat, tmat);
  } else {
    convert_f32_f16<<<convBlocks, 256, 0, stream>>>(Wg, Wg16);
    convert_f32_f16<<<convBlocks, 256, 0, stream>>>(Wu, Wu16);
    gemm_gateup<<<dim3((D_FFN / 128) * (M / 256)), 512, 0, stream>>>(h16, Wg16, Wu16, cmat, Bmat, tmat);
    convert_f32_f16<<<convBlocks, 256, 0, stream>>>(Wd, Wd16);
  }
  gemm_down<<<dim3((D_MODEL / 128) * (M / 256)), 512, 0, stream>>>(tmat, Wd16, hs, out);
}

// Round 5
// 830.129 us; speedup vs baseline: 1.1181x; 1.1181x over previous
//
#include <hip/hip_runtime.h>
#include <cstdint>
#include <cstddef>

#define D_MODEL 2048
#define D_FFN   8192
#define RANK    16
#define EPS     1e-6f
#define MOD_SCALE 0.1f

typedef float    f32x4 __attribute__((ext_vector_type(4)));
typedef _Float16 half8 __attribute__((ext_vector_type(8)));

// Async global->LDS, 16B per lane. LDS dest is wave-uniform base + lane*16;
// the GLOBAL address is per-lane, so we XOR-swizzle the source 16B chunk
// (c ^ (row&7)) for bank-conflict-free ds_read_b128 later, at zero cost.
// Proven conflict-free ONLY with the 16x16 quad-based fragment addressing
// (frag64 below). Geometry everywhere: 64-half (128 B) row stride.
__device__ __forceinline__ void async_load16(const void* g, void* l) {
  __builtin_amdgcn_global_load_lds(
      (const __attribute__((address_space(1))) uint32_t*)g,
      (__attribute__((address_space(3))) uint32_t*)l,
      16, 0, 0);
}

// Stage one 32-row x 64-half (4 KB) round with 256 threads x 16 B.
// row = tid>>3 (0..31); rows per round = blockDim/8.
__device__ __forceinline__ void stage_round(const _Float16* __restrict__ g,
                                            size_t stride, _Float16* l, int tid) {
  const int row = tid >> 3;
  const int cs  = (tid & 7) ^ (row & 7);
  async_load16(g + (size_t)row * stride + (size_t)cs * 8, l + tid * 8);
}

// Read 8-half fragment at (row, 8-half chunk ck) from a swizzled 64-wide tile.
__device__ __forceinline__ half8 frag64(const _Float16* base, int row, int ck) {
  return *(const half8*)&base[row * 64 + ((ck ^ (row & 7)) * 8)];
}

#define PRIO1() __builtin_amdgcn_s_setprio(1)
#define PRIO0() __builtin_amdgcn_s_setprio(0)
#define VMW(n)  asm volatile("s_waitcnt vmcnt(" #n ")" ::: "memory")
// Raw barrier WITH compiler memory fence (no waitcnt drain emitted, unlike
// __syncthreads): no LDS/global op may be moved across it by the scheduler.
#define BARM()  asm volatile("s_barrier" ::: "memory")

// ---------------------------------------------------------------------------
// Fused fp32 -> f16 convert for all three big weights (one launch).
// ---------------------------------------------------------------------------
__global__ __launch_bounds__(256) void convert3_f32_f16(
    const float* __restrict__ s0, const float* __restrict__ s1,
    const float* __restrict__ s2,
    _Float16* __restrict__ d0, _Float16* __restrict__ d1,
    _Float16* __restrict__ d2)
{
  const int w = blockIdx.x >> 13;
  const float*   s = (w == 0) ? s0 : (w == 1) ? s1 : s2;
  _Float16*      d = (w == 0) ? d0 : (w == 1) ? d1 : d2;
  size_t i = ((size_t)(blockIdx.x & 8191) * 256 + threadIdx.x) * 8;
  f32x4 a = *(const f32x4*)(s + i);
  f32x4 b = *(const f32x4*)(s + i + 4);
  half8 h;
  #pragma unroll
  for (int j = 0; j < 4; ++j) { h[j] = (_Float16)a[j]; h[4+j] = (_Float16)b[j]; }
  *(half8*)(d + i) = h;
}

__global__ __launch_bounds__(256) void convert_f32_f16(
    const float* __restrict__ s, _Float16* __restrict__ d)
{
  size_t i = ((size_t)blockIdx.x * 256 + threadIdx.x) * 8;
  f32x4 a = *(const f32x4*)(s + i);
  f32x4 b = *(const f32x4*)(s + i + 4);
  half8 h;
  #pragma unroll
  for (int j = 0; j < 4; ++j) { h[j] = (_Float16)a[j]; h[4+j] = (_Float16)b[j]; }
  *(half8*)(d + i) = h;
}

// ---------------------------------------------------------------------------
// Kernel 1: per-token RMSNorm -> h (f16), c[m,r] = (h.A)[r] * 0.1*tanh((attn.A)[r])
// ---------------------------------------------------------------------------
__global__ __launch_bounds__(256) void prep_kernel(
    const float* __restrict__ hs, const float* __restrict__ attn,
    const float* __restrict__ Amat, const float* __restrict__ gamma,
    _Float16* __restrict__ h16, float* __restrict__ cmat)
{
  const int token = blockIdx.x;
  const int tid   = threadIdx.x;
  const int lane  = tid & 63;
  const int wv    = tid >> 6;
  const size_t tb = (size_t)token * D_MODEL;
  const int base  = tid * 8;

  f32x4 x0 = *(const f32x4*)(hs + tb + base);
  f32x4 x1 = *(const f32x4*)(hs + tb + base + 4);
  f32x4 a0 = *(const f32x4*)(attn + tb + base);
  f32x4 a1 = *(const f32x4*)(attn + tb + base + 4);

  float ss = 0.f;
  #pragma unroll
  for (int j = 0; j < 4; ++j) ss += x0[j]*x0[j] + x1[j]*x1[j];
  #pragma unroll
  for (int off = 32; off > 0; off >>= 1) ss += __shfl_xor(ss, off, 64);

  __shared__ float red[4];
  __shared__ float redp[4][RANK];
  __shared__ float redh[4][RANK];
  if (lane == 0) red[wv] = ss;
  __syncthreads();
  const float tot = red[0] + red[1] + red[2] + red[3];
  const float rms = rsqrtf(tot * (1.0f / D_MODEL) + EPS);

  f32x4 g0 = *(const f32x4*)(gamma + base);
  f32x4 g1 = *(const f32x4*)(gamma + base + 4);
  float hv[8], av[8];
  #pragma unroll
  for (int j = 0; j < 4; ++j) {
    hv[j]   = x0[j] * rms * g0[j];
    hv[4+j] = x1[j] * rms * g1[j];
    av[j]   = a0[j];
    av[4+j] = a1[j];
  }
  half8 hh;
  #pragma unroll
  for (int j = 0; j < 8; ++j) hh[j] = (_Float16)hv[j];
  *(half8*)(h16 + tb + base) = hh;

  float pa[RANK], ph[RANK];
  #pragma unroll
  for (int r = 0; r < RANK; ++r) { pa[r] = 0.f; ph[r] = 0.f; }
  #pragma unroll
  for (int e = 0; e < 8; ++e) {
    const f32x4* Ar = (const f32x4*)(Amat + (size_t)(base + e) * RANK);
    #pragma unroll
    for (int q = 0; q < 4; ++q) {
      f32x4 ar = Ar[q];
      #pragma unroll
      for (int j = 0; j < 4; ++j) {
        pa[q*4+j] += av[e] * ar[j];
        ph[q*4+j] += hv[e] * ar[j];
      }
    }
  }
  #pragma unroll
  for (int r = 0; r < RANK; ++r) {
    #pragma unroll
    for (int off = 32; off > 0; off >>= 1) {
      pa[r] += __shfl_xor(pa[r], off, 64);
      ph[r] += __shfl_xor(ph[r], off, 64);
    }
  }
  if (lane == 0) {
    #pragma unroll
    for (int r = 0; r < RANK; ++r) { redp[wv][r] = pa[r]; redh[wv][r] = ph[r]; }
  }
  __syncthreads();
  if (tid < RANK) {
    float sp = redp[0][tid] + redp[1][tid] + redp[2][tid] + redp[3][tid];
    float sh = redh[0][tid] + redh[1][tid] + redh[2][tid] + redh[3][tid];
    cmat[(size_t)token * RANK + tid] = sh * (MOD_SCALE * tanhf(sp));
  }
}

// ---------------------------------------------------------------------------
// Kernel 2: dual GEMM, 256x128 tile, BK=64, FOUR waves (2M x 2N).
// R5: traffic-ratio attack. Each wave owns a 128x64 DUAL tile (gate+up share
// the wave's A-fragments): LDS bytes/FLOP drop 22.9 -> 15.6 B/KFLOP; block
// LDS read per K-step 192 -> 128 KB. acc = 256 VGPR (accG[8][4]+accU[8][4]);
// __launch_bounds__(256,1) -> 512-VGPR cap, no spill expected (~410 live).
// Loop = R2-verified single-barrier double-buffer: stage(t+1) at tile top
// (VMW(0) pre-landed under ~2500 cyc of compute), ck1 B-reads issued between
// the two MFMA clusters. WRITE_SIZE is the spill tripwire (65536 = clean).
// ---------------------------------------------------------------------------
#define BGOFF 16384
#define BUOFF 24576

__global__ __launch_bounds__(256, 1) void gemm_gateup(
    const _Float16* __restrict__ h16,
    const _Float16* __restrict__ Wg16, const _Float16* __restrict__ Wu16,
    const float* __restrict__ cmat, const float* __restrict__ Bmat,
    _Float16* __restrict__ tmat)
{
  __shared__ __align__(16) _Float16 lds[2][32768];   // 128 KB: A 32K | Bg 16K | Bu 16K

  const int tid  = threadIdx.x;
  const int lane = tid & 63;
  const int wv   = tid >> 6;          // 0..3
  const int lr   = lane & 15;
  const int quad = lane >> 4;
  const int wm   = (wv >> 1) * 128;   // wave row base (M)
  const int wn   = (wv & 1) * 64;     // wave col base (N)

  // XCD-partitioned mapping (native dispatch: lin%8 -> XCD):
  // xcd owns m-tiles {2*xcd, 2*xcd+1}; within-XCD order n-fast, m-pair inner.
  const int lin  = blockIdx.x;
  const int xcd  = lin & 7;
  const int r    = lin >> 3;                 // 0..127
  const int gm0  = (xcd * 2 + (r & 1)) * 256;
  const int gn0  = (r >> 1) * 128;

  f32x4 accG[8][4], accU[8][4];
  #pragma unroll
  for (int i = 0; i < 8; ++i)
    #pragma unroll
    for (int j = 0; j < 4; ++j) {
      f32x4 z = {0.f, 0.f, 0.f, 0.f};
      accG[i][j] = z; accU[i][j] = z;
    }

  // Stage a full K-tile t into buffer b: 16 rounds x 4 KB (32 rows each).
#define STAGE_ALL(b,t) do {                                                          \
    _Pragma("unroll")                                                                \
    for (int j = 0; j < 8; ++j)                                                      \
      stage_round(h16  + (size_t)(gm0 + j*32) * D_MODEL + (size_t)(t)*64, D_MODEL,   \
                  &lds[b][j*2048], tid);                                             \
    _Pragma("unroll")                                                                \
    for (int j = 0; j < 4; ++j)                                                      \
      stage_round(Wg16 + (size_t)(gn0 + j*32) * D_MODEL + (size_t)(t)*64, D_MODEL,   \
                  &lds[b][BGOFF + j*2048], tid);                                     \
    _Pragma("unroll")                                                                \
    for (int j = 0; j < 4; ++j)                                                      \
      stage_round(Wu16 + (size_t)(gn0 + j*32) * D_MODEL + (size_t)(t)*64, D_MODEL,   \
                  &lds[b][BUOFF + j*2048], tid);                                     \
  } while (0)

  // Prologue: tile 0 staged and landed.
  STAGE_ALL(0, 0);
  VMW(0); BARM();

  constexpr int NT = D_MODEL / 64;    // 32
  for (int t = 0; t < NT; ++t) {
    const int cur = t & 1, nxt = cur ^ 1;
    // Issue next tile's staging first: lands during this tile's MFMAs.
    if (t + 1 < NT) STAGE_ALL(nxt, t + 1);

    const _Float16* A_  = &lds[cur][wm * 64];          // wave's 128 A-rows
    const _Float16* Bg_ = &lds[cur][BGOFF + wn * 64];  // wave's 64 B-rows
    const _Float16* Bu_ = &lds[cur][BUOFF + wn * 64];

    half8 a0[8], a1[8], bg[4], bu[4];
    #pragma unroll
    for (int im = 0; im < 8; ++im) a0[im] = frag64(A_, im*16 + lr, quad);
    #pragma unroll
    for (int inn = 0; inn < 4; ++inn) {
      bg[inn] = frag64(Bg_, inn*16 + lr, quad);
      bu[inn] = frag64(Bu_, inn*16 + lr, quad);
    }
    #pragma unroll
    for (int im = 0; im < 8; ++im) a1[im] = frag64(A_, im*16 + lr, 4 + quad);

    PRIO1();
    #pragma unroll
    for (int im = 0; im < 8; ++im)
      #pragma unroll
      for (int inn = 0; inn < 4; ++inn) {
        accG[im][inn] = __builtin_amdgcn_mfma_f32_16x16x32_f16(a0[im], bg[inn], accG[im][inn], 0, 0, 0);
        accU[im][inn] = __builtin_amdgcn_mfma_f32_16x16x32_f16(a0[im], bu[inn], accU[im][inn], 0, 0, 0);
      }
    PRIO0();

    // ck1 B-fragments (reuse bg/bu registers; service overlaps cluster above).
    #pragma unroll
    for (int inn = 0; inn < 4; ++inn) {
      bg[inn] = frag64(Bg_, inn*16 + lr, 4 + quad);
      bu[inn] = frag64(Bu_, inn*16 + lr, 4 + quad);
    }
    PRIO1();
    #pragma unroll
    for (int im = 0; im < 8; ++im)
      #pragma unroll
      for (int inn = 0; inn < 4; ++inn) {
        accG[im][inn] = __builtin_amdgcn_mfma_f32_16x16x32_f16(a1[im], bg[inn], accG[im][inn], 0, 0, 0);
        accU[im][inn] = __builtin_amdgcn_mfma_f32_16x16x32_f16(a1[im], bu[inn], accU[im][inn], 0, 0, 0);
      }
    PRIO0();

    // stage(t+1) had the whole tile's compute to land -> wait is pre-landed.
    VMW(0); BARM();
  }

  // ---- rank-16 delta folded in as one zero-padded K=32 MFMA step into accG ----
  __syncthreads();   // full drain; loop is done
  _Float16* l0 = &lds[0][0];
  for (int i = tid; i < 8192; i += 256) {           // cbuf [256][32]
    int m = i >> 5, k = i & 31;
    l0[i] = (k < RANK) ? (_Float16)cmat[(size_t)(gm0 + m) * RANK + k] : (_Float16)0.f;
  }
  for (int i = tid; i < 4096; i += 256) {           // bbuf [128][32]
    int f = i >> 5, k = i & 31;
    l0[8192 + i] = (k < RANK) ? (_Float16)Bmat[(size_t)k * D_FFN + gn0 + f] : (_Float16)0.f;
  }
  __syncthreads();
  #pragma unroll
  for (int ai = 0; ai < 8; ++ai) {
    half8 cf = *(const half8*)&l0[(wm + ai*16 + lr) * 32 + quad * 8];
    #pragma unroll
    for (int inn = 0; inn < 4; ++inn) {
      half8 bd = *(const half8*)&l0[8192 + (wn + inn*16 + lr) * 32 + quad * 8];
      accG[ai][inn] = __builtin_amdgcn_mfma_f32_16x16x32_f16(cf, bd, accG[ai][inn], 0, 0, 0);
    }
  }

  // ---- Epilogue: t = silu(gate) * up ----
  #pragma unroll
  for (int ai = 0; ai < 8; ++ai)
    #pragma unroll
    for (int inn = 0; inn < 4; ++inn) {
      const int grow = gm0 + wm + ai*16 + quad*4;
      const int gcol = gn0 + wn + inn*16 + lr;
      #pragma unroll
      for (int rr = 0; rr < 4; ++rr) {
        float g = accG[ai][inn][rr];
        float u = accU[ai][inn][rr];
        float s = g / (1.0f + __expf(-g));
        tmat[(size_t)(grow + rr) * D_FFN + gcol] = (_Float16)(s * u);
      }
    }
#undef STAGE_ALL
}

// ---------------------------------------------------------------------------
// Kernel 3: out = hidden_states + t @ Wd16^T (K=8192). 256x128 tile, BK=64,
// FOUR waves (2M x 2N), wave tile 128x64: LDS read/K-step 160 -> 96 KB.
// 2-buffer LDS (96 KB), single-barrier double-buffer loop (as gateup).
// Grid = exactly 256 blocks (1/CU); XCD mapping keeps each XCD's 2 Wd
// n-panels (4 MB) L2-resident.
// ---------------------------------------------------------------------------
__global__ __launch_bounds__(256, 1) void gemm_down(
    const _Float16* __restrict__ tmat, const _Float16* __restrict__ Wd16,
    const float* __restrict__ hs, float* __restrict__ out)
{
  __shared__ __align__(16) _Float16 lds[2][24576];   // 96 KB: A 32 KB | B 16 KB

  const int tid  = threadIdx.x;
  const int lane = tid & 63;
  const int wv   = tid >> 6;          // 0..3
  const int lr   = lane & 15;
  const int quad = lane >> 4;
  const int wm   = (wv >> 1) * 128;
  const int wn   = (wv & 1) * 64;

  const int lin  = blockIdx.x;               // 256 blocks
  const int xcd  = lin & 7;
  const int r    = lin >> 3;                 // 0..31
  const int gn0  = (xcd * 2 + (r & 1)) * 128;
  const int gm0  = (r >> 1) * 256;

  constexpr int NT = D_FFN / 64;          // 128

  f32x4 acc[8][4];
  #pragma unroll
  for (int i = 0; i < 8; ++i)
    #pragma unroll
    for (int j = 0; j < 4; ++j) {
      f32x4 z = {0.f, 0.f, 0.f, 0.f};
      acc[i][j] = z;
    }

#define DSTAGE_ALL(b,t) do {                                                         \
    _Pragma("unroll")                                                                \
    for (int j = 0; j < 8; ++j)                                                      \
      stage_round(tmat + (size_t)(gm0 + j*32) * D_FFN + (size_t)(t)*64, D_FFN,       \
                  &lds[b][j*2048], tid);                                             \
    _Pragma("unroll")                                                                \
    for (int j = 0; j < 4; ++j)                                                      \
      stage_round(Wd16 + (size_t)(gn0 + j*32) * D_FFN + (size_t)(t)*64, D_FFN,       \
                  &lds[b][16384 + j*2048], tid);                                     \
  } while (0)

  // Prologue: tile 0 staged and landed.
  DSTAGE_ALL(0, 0);
  VMW(0); BARM();

  for (int t = 0; t < NT; ++t) {
    const int cur = t & 1, nxt = cur ^ 1;
    if (t + 1 < NT) DSTAGE_ALL(nxt, t + 1);

    const _Float16* A_ = &lds[cur][wm * 64];
    const _Float16* B_ = &lds[cur][16384 + wn * 64];

    half8 a0[8], a1[8], b0[4];
    #pragma unroll
    for (int im = 0; im < 8; ++im) a0[im] = frag64(A_, im*16 + lr, quad);
    #pragma unroll
    for (int inn = 0; inn < 4; ++inn) b0[inn] = frag64(B_, inn*16 + lr, quad);
    #pragma unroll
    for (int im = 0; im < 8; ++im) a1[im] = frag64(A_, im*16 + lr, 4 + quad);

    PRIO1();
    #pragma unroll
    for (int im = 0; im < 8; ++im)
      #pragma unroll
      for (int inn = 0; inn < 4; ++inn)
        acc[im][inn] = __builtin_amdgcn_mfma_f32_16x16x32_f16(a0[im], b0[inn], acc[im][inn], 0, 0, 0);
    PRIO0();

    #pragma unroll
    for (int inn = 0; inn < 4; ++inn) b0[inn] = frag64(B_, inn*16 + lr, 4 + quad);
    PRIO1();
    #pragma unroll
    for (int im = 0; im < 8; ++im)
      #pragma unroll
      for (int inn = 0; inn < 4; ++inn)
        acc[im][inn] = __builtin_amdgcn_mfma_f32_16x16x32_f16(a1[im], b0[inn], acc[im][inn], 0, 0, 0);
    PRIO0();

    VMW(0); BARM();
  }

  #pragma unroll
  for (int ai = 0; ai < 8; ++ai)
    #pragma unroll
    for (int inn = 0; inn < 4; ++inn) {
      const int grow = gm0 + wm + ai*16 + quad*4;
      const int gcol = gn0 + wn + inn*16 + lr;
      #pragma unroll
      for (int rr = 0; rr < 4; ++rr) {
        size_t o = (size_t)(grow + rr) * D_MODEL + gcol;
        out[o] = hs[o] + acc[ai][inn][rr];
      }
    }
#undef DSTAGE_ALL
}

extern "C" void kernel_launch(void* const* d_in, const int* in_sizes, int n_in,
                              void* d_out, int out_size, void* d_ws, size_t ws_size,
                              hipStream_t stream) {
  const float* hs    = (const float*)d_in[0];
  const float* attn  = (const float*)d_in[1];
  const float* Amat  = (const float*)d_in[2];
  const float* Bmat  = (const float*)d_in[3];
  const float* Wg    = (const float*)d_in[4];
  const float* Wu    = (const float*)d_in[5];
  const float* Wd    = (const float*)d_in[6];
  const float* gamma = (const float*)d_in[7];
  float* out = (float*)d_out;

  const int M = in_sizes[0] / D_MODEL;        // 4096 tokens
  const size_t WD = (size_t)D_FFN * D_MODEL;  // elements per big weight

  char* ws = (char*)d_ws;
  _Float16* h16  = (_Float16*)ws;
  float*    cmat = (float*)(ws + (size_t)M * D_MODEL * 2);
  _Float16* tmat = (_Float16*)(ws + (size_t)M * D_MODEL * 2 + (size_t)M * RANK * 4);
  _Float16* wbuf = tmat + (size_t)M * D_FFN;
  _Float16* Wg16 = wbuf;
  _Float16* Wu16 = wbuf + WD;

  const size_t base_bytes = (size_t)M * D_MODEL * 2 + (size_t)M * RANK * 4
                          + (size_t)M * D_FFN * 2 + 2 * WD * 2;
  const bool sep_wd = (ws_size >= base_bytes + WD * 2);
  _Float16* Wd16 = sep_wd ? (wbuf + 2 * WD) : wbuf;   // else reuse Wg16 slot

  const int convBlocks = (int)(WD / (256 * 8));   // 8192 per weight

  prep_kernel<<<M, 256, 0, stream>>>(hs, attn, Amat, gamma, h16, cmat);
  if (sep_wd) {
    convert3_f32_f16<<<3 * convBlocks, 256, 0, stream>>>(Wg, Wu, Wd, Wg16, Wu16, Wd16);
    gemm_gateup<<<dim3((D_FFN / 128) * (M / 256)), 256, 0, stream>>>(h16, Wg16, Wu16, cmat, Bmat, tmat);
  } else {
    convert_f32_f16<<<convBlocks, 256, 0, stream>>>(Wg, Wg16);
    convert_f32_f16<<<convBlocks, 256, 0, stream>>>(Wu, Wu16);
    gemm_gateup<<<dim3((D_FFN / 128) * (M / 256)), 256, 0, stream>>>(h16, Wg16, Wu16, cmat, Bmat, tmat);
    convert_f32_f16<<<convBlocks, 256, 0, stream>>>(Wd, Wd16);
  }
  gemm_down<<<dim3((D_MODEL / 128) * (M / 256)), 256, 0, stream>>>(tmat, Wd16, hs, out);
}